// Round 8
// baseline (140.287 us; speedup 1.0000x reference)
//
#include <hip/hip_runtime.h>
#include <math.h>

// JointAttentionMemoryBank via fp16 32x32x16 MFMA.
//   out = W @ softmax(W^T x / sqrt(D)),  B=16 N=4096 D=128 M=1536, fp32 in/out.
// R8: (1) v_mfma_f32_32x32x16_f16 — 2x FLOP per 16B fragment halves LDS
// bytes/FLOP (R7 counters: LDS pipe ~87% busy incl. 43K cyc/CU conflicts);
// (2) XOR-swizzled xs/Pbuf (granule ^= row&15) — uniform banks, keeps 16B
// alignment (aligned padding provably leaves gcd>=4 -> 4-way conflicts);
// (3) simple R6 2-barrier sessions (R7 pipelining was neutral).
// 12 sessions x 128 m; wave w owns m-tile q*4+w (ph1) and d-tile w (ph2).
// LDS 33 KB -> 4 blocks/CU; regs ~64 AGPR + ~45 VGPR < 128 (4 waves/SIMD).
// A/B lane maps (32x32x16): row = lane&31, k = (lane>>5)*8 + j.
// C/D (HW-verified): col = lane&31, row = (reg&3) + 8*(reg>>2) + 4*(lane>>5).

#define Bdim 16
#define Ndim 4096
#define Ddim 128
#define Mdim 1536
#define NT 64               // rows (n) per block
#define NTHREADS 256        // 4 waves
#define NSESS 12            // m-sessions of 128
#define NFRAG 24576         // fragments per W array = D*M/8

typedef __attribute__((ext_vector_type(8)))  _Float16 f16x8;   // 4 VGPRs (A/B)
typedef __attribute__((ext_vector_type(4)))  _Float16 f16x4;   // 8 B
typedef __attribute__((ext_vector_type(16))) float    f32x16;  // 32x32 C/D

// ---- prep: W (D,M) fp32 -> fragment-ordered fp16 arrays (gather form) ----
// wt (phase-1 A = W^T, pre-scaled 1/sqrt(D)), mt in [0,48), ks in [0,8):
//   frag f = (mt*8 + ks)*64 + l ; m = mt*32 + (l&31), d = ks*16 + (l>>5)*8 + j
// wd (phase-2 A = W), dt in [0,4), km in [0,96):
//   frag f = (dt*96 + km)*64 + l ; d = dt*32 + (l&31), m = km*16 + (l>>5)*8 + j
__global__ void jamb_prep(const float* __restrict__ w,
                          _Float16* __restrict__ wt,
                          _Float16* __restrict__ wd) {
    const int tid = blockIdx.x * 256 + threadIdx.x;   // [0, 2*NFRAG)
    const float SC = 0.08838834764831843f;            // 1/sqrt(128)
    if (tid < NFRAG) {                                // blocks 0..95: wt
        const int f    = tid;
        const int l    = f & 63;
        const int fs   = f >> 6;
        const int ks   = fs & 7;          // 0..7
        const int mt   = fs >> 3;         // 0..47
        const int m    = mt * 32 + (l & 31);
        const int d0   = ks * 16 + (l >> 5) * 8;
        f16x8 pk;
        #pragma unroll
        for (int j = 0; j < 8; ++j)
            pk[j] = (_Float16)(w[(size_t)(d0 + j) * Mdim + m] * SC);
        *(f16x8*)&wt[(size_t)f * 8] = pk;
    } else {                                          // blocks 96..191: wd
        const int f    = tid - NFRAG;
        const int l    = f & 63;
        const int fs   = f >> 6;
        const int km   = fs % 96;         // 0..95
        const int dt   = fs / 96;         // 0..3
        const int d    = dt * 32 + (l & 31);
        const int m0   = km * 16 + (l >> 5) * 8;
        const float* src = w + (size_t)d * Mdim + m0;
        const float4 v0 = *(const float4*)src;
        const float4 v1 = *(const float4*)(src + 4);
        f16x8 pk;
        pk[0] = (_Float16)v0.x; pk[1] = (_Float16)v0.y;
        pk[2] = (_Float16)v0.z; pk[3] = (_Float16)v0.w;
        pk[4] = (_Float16)v1.x; pk[5] = (_Float16)v1.y;
        pk[6] = (_Float16)v1.z; pk[7] = (_Float16)v1.w;
        *(f16x8*)&wd[(size_t)f * 8] = pk;
    }
}

__global__ __launch_bounds__(NTHREADS, 4)
void jamb_mfma_kernel(const float* __restrict__ x,
                      const _Float16* __restrict__ wt,
                      const _Float16* __restrict__ wd,
                      float* __restrict__ out) {
    // Swizzled tiles: elem (row, col) lives at row*128 + ((col>>3) ^ (row&15))*8 + (col&7).
    __shared__ __align__(16) _Float16 xs[NT * 128];    // 16384 B  (cols = d)
    __shared__ __align__(16) _Float16 Pbuf[NT * 128];  // 16384 B  (cols = session m)
    __shared__ float redsum[4][NT];                    // 1024 B   (total 33792 B)

    const int t    = threadIdx.x;
    const int w    = t >> 6;        // wave 0..3
    const int l    = t & 63;
    const int c32  = l & 31;        // col within 32-tile (n for C; row for A frags)
    const int half = l >> 5;        // k-half selector in A/B frags

    const int blk   = blockIdx.x;
    const int b     = blk >> 6;             // 64 blocks per batch
    const int nbase = (blk & 63) * NT;

    // ---- stage x tile -> LDS fp16, swizzled (coalesced float4 reads) ----
    {
        const float* xb = x + (size_t)(b * Ndim + nbase) * Ddim;
        #pragma unroll
        for (int i = 0; i < 8; ++i) {
            const int f   = t + i * 256;        // float4 index [0,2048)
            const int row = f >> 5;             // n row 0..63
            const int c4  = (f & 31) * 4;       // d col 0,4,...,124
            const float4 v = *(const float4*)(xb + row * Ddim + c4);
            f16x4 pk;
            pk[0] = (_Float16)v.x; pk[1] = (_Float16)v.y;
            pk[2] = (_Float16)v.z; pk[3] = (_Float16)v.w;
            const int g = ((c4 >> 3) ^ (row & 15)) << 3;   // swizzled granule base
            *(f16x4*)&xs[row * 128 + g + (c4 & 7)] = pk;
        }
    }
    __syncthreads();

    const f16x8* WT = (const f16x8*)wt;
    const f16x8* WD = (const f16x8*)wd;

    float sums[2] = {0.f, 0.f};                  // unnormalized softmax sums per n-tile col
    f32x16 c0 = {0.f}, c1 = {0.f};               // phase-2 acc: d-tile w, n-tiles 0/1
    #pragma unroll
    for (int r = 0; r < 16; ++r) { c0[r] = 0.f; c1[r] = 0.f; }

    const int swz = c32 & 15;                    // swizzle key (same for both n-tiles)

    #pragma unroll 1
    for (int q = 0; q < NSESS; ++q) {
        // ---- phase 1: m-tile q*4+w (32 m) x 2 n-tiles, K = 128 in 8 steps ----
        f32x16 a0 = {0.f}, a1 = {0.f};
        #pragma unroll
        for (int r = 0; r < 16; ++r) { a0[r] = 0.f; a1[r] = 0.f; }
        #pragma unroll
        for (int ks = 0; ks < 8; ++ks) {
            const f16x8 af = WT[((q * 4 + w) * 8 + ks) * 64 + l];
            const int g = (((ks * 2 + half) ^ swz) << 3);
            const f16x8 b0 = *(const f16x8*)&xs[c32 * 128 + g];
            const f16x8 b1 = *(const f16x8*)&xs[(32 + c32) * 128 + g];
            a0 = __builtin_amdgcn_mfma_f32_32x32x16_f16(af, b0, a0, 0, 0, 0);
            a1 = __builtin_amdgcn_mfma_f32_32x32x16_f16(af, b1, a1, 0, 0, 0);
        }

        // ---- exp + swizzled P write (session m_local = w*32 + rq*8 + half*4 + 0..3) ----
        #pragma unroll
        for (int rq = 0; rq < 4; ++rq) {
            const int gq = ((w * 4 + rq) ^ swz) << 3;
            const int oq = half * 4;
            {
                const float e0 = __expf(a0[rq * 4 + 0]);
                const float e1 = __expf(a0[rq * 4 + 1]);
                const float e2 = __expf(a0[rq * 4 + 2]);
                const float e3 = __expf(a0[rq * 4 + 3]);
                sums[0] += (e0 + e1) + (e2 + e3);
                f16x4 pk;
                pk[0] = (_Float16)e0; pk[1] = (_Float16)e1;
                pk[2] = (_Float16)e2; pk[3] = (_Float16)e3;
                *(f16x4*)&Pbuf[c32 * 128 + gq + oq] = pk;
            }
            {
                const float e0 = __expf(a1[rq * 4 + 0]);
                const float e1 = __expf(a1[rq * 4 + 1]);
                const float e2 = __expf(a1[rq * 4 + 2]);
                const float e3 = __expf(a1[rq * 4 + 3]);
                sums[1] += (e0 + e1) + (e2 + e3);
                f16x4 pk;
                pk[0] = (_Float16)e0; pk[1] = (_Float16)e1;
                pk[2] = (_Float16)e2; pk[3] = (_Float16)e3;
                *(f16x4*)&Pbuf[(32 + c32) * 128 + gq + oq] = pk;
            }
        }
        __syncthreads();   // P session published

        // ---- phase 2: d-tile w, 8 m-ksteps of 16, both n-tiles ----
        #pragma unroll
        for (int km = 0; km < 8; ++km) {
            const f16x8 wdf = WD[(w * 96 + q * 8 + km) * 64 + l];
            const int g = (((km * 2 + half) ^ swz) << 3);
            const f16x8 p0 = *(const f16x8*)&Pbuf[c32 * 128 + g];
            const f16x8 p1 = *(const f16x8*)&Pbuf[(32 + c32) * 128 + g];
            c0 = __builtin_amdgcn_mfma_f32_32x32x16_f16(wdf, p0, c0, 0, 0, 0);
            c1 = __builtin_amdgcn_mfma_f32_32x32x16_f16(wdf, p1, c1, 0, 0, 0);
        }
        __syncthreads();   // Pbuf free for next session
    }

    // ---- softmax sums: lanes l and l^32 share column n; then cross-wave ----
    sums[0] += __shfl_xor(sums[0], 32, 64);
    sums[1] += __shfl_xor(sums[1], 32, 64);
    if (half == 0) {
        redsum[w][c32]      = sums[0];
        redsum[w][32 + c32] = sums[1];
    }
    __syncthreads();

    const float inv0 = 1.f / (redsum[0][c32] + redsum[1][c32] +
                              redsum[2][c32] + redsum[3][c32]);
    const float inv1 = 1.f / (redsum[0][32 + c32] + redsum[1][32 + c32] +
                              redsum[2][32 + c32] + redsum[3][32 + c32]);

    // ---- epilogue: C rows d = w*32 + rq*8 + half*4 + 0..3, col n = ntile*32 + c32 ----
    #pragma unroll
    for (int rq = 0; rq < 4; ++rq) {
        const int d = w * 32 + rq * 8 + half * 4;
        {
            float* op = out + (size_t)(b * Ndim + nbase + c32) * Ddim + d;
            float4 o;
            o.x = c0[rq * 4 + 0] * inv0; o.y = c0[rq * 4 + 1] * inv0;
            o.z = c0[rq * 4 + 2] * inv0; o.w = c0[rq * 4 + 3] * inv0;
            *(float4*)op = o;
        }
        {
            float* op = out + (size_t)(b * Ndim + nbase + 32 + c32) * Ddim + d;
            float4 o;
            o.x = c1[rq * 4 + 0] * inv1; o.y = c1[rq * 4 + 1] * inv1;
            o.z = c1[rq * 4 + 2] * inv1; o.w = c1[rq * 4 + 3] * inv1;
            *(float4*)op = o;
        }
    }
}

extern "C" void kernel_launch(void* const* d_in, const int* in_sizes, int n_in,
                              void* d_out, int out_size, void* d_ws, size_t ws_size,
                              hipStream_t stream) {
    const float* x = (const float*)d_in[0];   // (B,N,D)
    const float* w = (const float*)d_in[1];   // (1,D,M)
    float* out = (float*)d_out;
    (void)in_sizes; (void)n_in; (void)out_size; (void)ws_size;

    _Float16* wt = (_Float16*)d_ws;           // 384 KB
    _Float16* wd = wt + Ddim * Mdim;          // 384 KB

    jamb_prep<<<dim3((2 * NFRAG) / 256), dim3(256), 0, stream>>>(w, wt, wd);  // 192 blocks
    jamb_mfma_kernel<<<dim3((Bdim * Ndim) / NT), dim3(NTHREADS), 0, stream>>>(x, wt, wd, out);
}